// Round 8
// baseline (67.918 us; speedup 1.0000x reference)
//
#include <hip/hip_runtime.h>
#include <stdint.h>

// DSN few-shot classifier, MI355X.
// out[q][w] = log_softmax_w( ||P9_w q||^2 ),  query-norm cancels in softmax.
// P9 = P_colspace - u_min u_min^T, so s_w = ||B^T q||^2 - (u_min . q)^2 with
// B = M L^{-T} D^{-1/2} (G = L D L^T) an exact ONB of colspace(M).
//
// R7: eig solves the 5 ways in 5 PARALLEL WAVES (one way per wave, lanes 0-9,
// readlane comms with compile-time lane indices); serial path shrunk to
// 8 bisection rounds + 5 inverse-iteration solves in tight I-cached loops.
// gram/basis restored to the R1 parallel kernels (proven ~2us each) so
// rocprof attributes eig exactly.
//
// ws layout:
//   [0,      4000)  G    : 5*10*10 double
//   [4096,   6296)  W    : 5*11*10 float (rows 0..9: basis coeffs; row 10: v_min/|Mv|)
//   [6400,   6600)  idx  : 5*10 int
//   [8192, 172032)  Upad : 80*1024 bf16 (way w -> rows 16w..16w+10; rest zero)

typedef __attribute__((ext_vector_type(4))) float f32x4;
typedef __attribute__((ext_vector_type(8))) short s16x8;

#define WS_G_OFF    0
#define WS_W_OFF    4096
#define WS_IDX_OFF  6400
#define WS_U_OFF    8192

__device__ __forceinline__ unsigned short f2bf(float f) {
  unsigned int u = __float_as_uint(f);
  u += 0x7FFFu + ((u >> 16) & 1u);   // round-to-nearest-even
  return (unsigned short)(u >> 16);
}

// broadcast lane l's value (within the wave) via v_readlane
__device__ __forceinline__ float rdl(float v, int l) {
  return __uint_as_float(__builtin_amdgcn_readlane(__float_as_uint(v), l));
}

// int64 vs int32 one-hot labels detection (validated R0).
__device__ __forceinline__ bool labels_int64(const int* L) {
  int cnt = 0; bool oddz = true;
  #pragma unroll
  for (int t = 0; t < 20; ++t) {
    int v = L[t];
    if (t & 1) { if (v) oddz = false; }
    else       { if (v) cnt++; }
  }
  return oddz && (cnt == 2);
}

__device__ __forceinline__ int cls_of(const int* L, bool is64, int i) {
  int best = -0x7fffffff, c = 0;
  #pragma unroll
  for (int j = 0; j < 5; ++j) {
    int v = is64 ? L[i * 10 + 2 * j] : L[i * 5 + j];
    if (v > best) { best = v; c = j; }
  }
  return c;
}

// ---------------- Kernel A1: Gram matrices, one wave per (w,a,b) pair -------
__global__ void dsn_gram(const float* __restrict__ support,
                         const int* __restrict__ labels,
                         double* __restrict__ G) {
  int wid  = blockIdx.x * 4 + (threadIdx.x >> 6);
  int lane = threadIdx.x & 63;
  if (wid >= 275) return;               // 5 ways * 55 upper-tri pairs
  int w = wid / 55, p = wid % 55;
  int a = 0;
  while (p >= 10 - a) { p -= 10 - a; a++; }
  int b = a + p;                        // a <= b

  bool is64 = labels_int64(labels);
  int myc = (lane < 50) ? cls_of(labels, is64, lane) : -1;
  unsigned long long mask = __ballot(lane < 50 && myc == w);

  unsigned long long m = mask;
  for (int i = 0; i < a; ++i) m &= m - 1;
  int ia = __ffsll((unsigned long long)m) - 1;
  m = mask;
  for (int i = 0; i < b; ++i) m &= m - 1;
  int ib = __ffsll((unsigned long long)m) - 1;

  const float* A = support + ia * 1024;
  const float* B = support + ib * 1024;
  double acc = 0.0;
  #pragma unroll
  for (int i = 0; i < 16; ++i) {
    int d = lane + 64 * i;
    acc += (double)A[d] * (double)B[d];
  }
  #pragma unroll
  for (int off = 32; off > 0; off >>= 1) acc += __shfl_xor(acc, off);
  if (lane == 0) {
    G[(w * 10 + a) * 10 + b] = acc;
    G[(w * 10 + b) * 10 + a] = acc;
  }
}

// -------- Kernel A2: subspace solve, 5 parallel waves (way w = wave w) ------
// Lanes 0-9 of each wave, readlane comms (compile-time lane ids), branchless
// bracket updates; 8 bisect rounds + 5 inverse-iteration solves.
__global__ __launch_bounds__(320, 1) void dsn_eig(const int* __restrict__ labels,
                                                  const double* __restrict__ G,
                                                  float* __restrict__ W,
                                                  int* __restrict__ idx) {
  __shared__ int cls[50];
  int t = threadIdx.x;
  int w = t >> 6, li = t & 63;
  bool is64 = labels_int64(labels);
  if (t < 50) cls[t] = cls_of(labels, is64, t);
  __syncthreads();
  if (t < 5) {
    int s = 0;
    for (int i = 0; i < 50; ++i)
      if (cls[i] == t) { idx[t * 10 + s] = i; s++; }
  }
  if (li >= 10) return;                 // wave-tail exit; solve is lanes 0-9

  float g[10];
  #pragma unroll
  for (int k = 0; k < 10; ++k) g[k] = (float)G[(w * 10 + li) * 10 + k];

  // Gershgorin bracket for lambda_min
  float diag = g[0];
  #pragma unroll
  for (int k = 1; k < 10; ++k) diag = (li == k) ? g[k] : diag;
  float asum = 0.f;
  #pragma unroll
  for (int k = 0; k < 10; ++k) asum += fabsf(g[k]);
  float loi = diag - (asum - fabsf(diag)), hii = diag;
  float lo = 1e30f, hi = 1e30f;
  #pragma unroll
  for (int u = 0; u < 10; ++u) {
    lo = fminf(lo, rdl(loi, u));
    hi = fminf(hi, rdl(hii, u));
  }
  lo = fmaxf(lo, 0.f);
  hi = hi + 1.f;

  // bisection on Sylvester inertia (distributed LDL^T), 8 rounds, branchless
  #pragma unroll 1
  for (int round = 0; round < 8; ++round) {
    float mid = 0.5f * (lo + hi);
    float a[10];
    #pragma unroll
    for (int k = 0; k < 10; ++k) a[k] = (li == k) ? (g[k] - mid) : g[k];
    int neg = 0;
    #pragma unroll
    for (int j = 0; j < 10; ++j) {
      float dj = rdl(a[j], j);
      if (fabsf(dj) < 1e-4f) dj = -1e-4f;   // inertia guard
      neg += (dj < 0.f) ? 1 : 0;
      float lij = a[j] * (1.f / dj);
      #pragma unroll
      for (int k = j + 1; k < 10; ++k) {
        float ajk = rdl(a[k], j);
        if (li > j) a[k] -= lij * ajk;
      }
    }
    bool up = (neg == 0);
    lo = up ? mid : lo;                      // branchless bracket update
    hi = up ? hi : mid;
  }
  float sigma = lo - (hi - lo) - 0.5f;       // strictly below lambda_min

  // factorize (G - sigma I) = L D L^T; keep my L-row + my 1/pivot
  float a[10], l[10], dinv_mine = 1.f;
  #pragma unroll
  for (int k = 0; k < 10; ++k) a[k] = (li == k) ? (g[k] - sigma) : g[k];
  #pragma unroll
  for (int j = 0; j < 10; ++j) {
    float dj = rdl(a[j], j);
    float inv = 1.f / dj;
    dinv_mine = (li == j) ? inv : dinv_mine;
    float lij = a[j] * inv;
    l[j] = (li > j) ? lij : 0.f;
    #pragma unroll
    for (int k = j + 1; k < 10; ++k) {
      float ajk = rdl(a[k], j);
      if (li > j) a[k] -= lij * ajk;
    }
  }
  // transpose once: lt[j] = L[j][li]
  float lt[10];
  #pragma unroll
  for (int j = 0; j < 10; ++j) lt[j] = 0.f;
  #pragma unroll
  for (int j = 1; j < 10; ++j) {
    #pragma unroll
    for (int k = 0; k < j; ++k) {
      float v = rdl(l[k], j);
      lt[j] = (li == k) ? v : lt[j];
    }
  }

  // inverse iteration, 5 solves (tight loop, I-cached)
  float y = 1.f;
  #pragma unroll 1
  for (int itr = 0; itr < 5; ++itr) {
    #pragma unroll
    for (int j = 0; j < 9; ++j) {          // forward: L z = y
      float yj = rdl(y, j);
      if (li > j) y -= l[j] * yj;
    }
    y *= dinv_mine;                        // D
    #pragma unroll
    for (int j = 9; j >= 1; --j) {         // back: L^T x = z
      float xj = rdl(y, j);
      if (li < j) y -= lt[j] * xj;
    }
    float am = fabsf(y), mx = 0.f;
    #pragma unroll
    for (int u = 0; u < 10; ++u) mx = fmaxf(mx, rdl(am, u));
    y *= (1.f / mx);
  }

  // row 10: v / ||M v||, ||M v||^2 = v^T G v
  float gv = 0.f;
  #pragma unroll
  for (int k = 0; k < 10; ++k) gv += g[k] * rdl(y, k);
  float contrib = gv * y, denom = 0.f;
  #pragma unroll
  for (int u = 0; u < 10; ++u) denom += rdl(contrib, u);
  float sc = 1.f / sqrtf(denom);
  W[(w * 11 + 10) * 10 + li] = y * sc;

  // factorize G = L D L^T (sigma=0); keep pivots + L row
  float dv[10];
  #pragma unroll
  for (int k = 0; k < 10; ++k) a[k] = g[k];
  #pragma unroll
  for (int j = 0; j < 10; ++j) {
    float dj = rdl(a[j], j);
    dv[j] = dj;
    float lij = a[j] * (1.f / dj);
    l[j] = (li > j) ? lij : 0.f;
    #pragma unroll
    for (int k = j + 1; k < 10; ++k) {
      float ajk = rdl(a[k], j);
      if (li > j) a[k] -= lij * ajk;
    }
  }
  #pragma unroll
  for (int j = 0; j < 10; ++j) lt[j] = 0.f;
  #pragma unroll
  for (int j = 1; j < 10; ++j) {
    #pragma unroll
    for (int k = 0; k < j; ++k) {
      float v = rdl(l[k], j);
      lt[j] = (li == k) ? v : lt[j];
    }
  }

  // X = L^{-T} (lane li holds row li), all 10 columns
  float X[10];
  #pragma unroll
  for (int r = 0; r < 10; ++r) X[r] = (li == r) ? 1.f : 0.f;
  #pragma unroll
  for (int j = 9; j >= 1; --j) {
    #pragma unroll
    for (int r = j; r < 10; ++r) {
      float xjr = rdl(X[r], j);
      if (li < j) X[r] -= lt[j] * xjr;
    }
  }
  // basis r coeffs = col r of L^{-T} D^{-1/2}
  #pragma unroll
  for (int r = 0; r < 10; ++r)
    W[(w * 11 + r) * 10 + li] = X[r] * (1.f / sqrtf(dv[r]));
}

// ---------------- Kernel A3: materialize Upad (80 x 1024 bf16) -------------
__global__ void dsn_basis(const float* __restrict__ support,
                          const float* __restrict__ W,
                          const int* __restrict__ idx,
                          unsigned short* __restrict__ U) {
  int r = blockIdx.x;              // 0..79
  int w = r >> 4, kk = r & 15;
  unsigned short* Urow = U + r * 1024;
  if (kk >= 11) {
    for (int d = threadIdx.x; d < 1024; d += 256) Urow[d] = 0;
    return;
  }
  float wv[10]; int id[10];
  #pragma unroll
  for (int s = 0; s < 10; ++s) {
    wv[s] = W[(w * 11 + kk) * 10 + s];
    id[s] = idx[w * 10 + s];
  }
  for (int d = threadIdx.x; d < 1024; d += 256) {
    float sum = 0.f;
    #pragma unroll
    for (int s = 0; s < 10; ++s) sum += support[id[s] * 1024 + d] * wv[s];
    Urow[d] = f2bf(sum);
  }
}

// ---------------- Kernel B: main — MFMA coeffs + log_softmax ---------------
// 16 queries per wave. A = Upad (5 row-tiles, one per way), B = Q^T fragment.
// D[row=channel][col=query]: col = lane&15, row = (lane>>4)*4 + reg  (m89).
// Row 10 (u_min) lives at lane-group 2, reg 2 -> its square is SUBTRACTED.
__global__ __launch_bounds__(256) void dsn_main(const float* __restrict__ query,
                                                const unsigned short* __restrict__ U,
                                                float* __restrict__ out) {
  int wid  = blockIdx.x * 4 + (threadIdx.x >> 6);
  int lane = threadIdx.x & 63;
  int q0   = wid * 16;
  int qrow = lane & 15;
  int kbase = (lane >> 4) * 8;

  const float* qp = query + (size_t)(q0 + qrow) * 1024 + kbase;
  const unsigned short* up = U + qrow * 1024 + kbase;

  f32x4 acc[5];
  #pragma unroll
  for (int w = 0; w < 5; ++w) acc[w] = (f32x4){0.f, 0.f, 0.f, 0.f};

  #pragma unroll 4
  for (int kt = 0; kt < 32; ++kt) {
    const float* qk = qp + kt * 32;
    f32x4 lo = *(const f32x4*)qk;
    f32x4 hi = *(const f32x4*)(qk + 4);
    s16x8 bf;
    bf[0] = (short)f2bf(lo[0]); bf[1] = (short)f2bf(lo[1]);
    bf[2] = (short)f2bf(lo[2]); bf[3] = (short)f2bf(lo[3]);
    bf[4] = (short)f2bf(hi[0]); bf[5] = (short)f2bf(hi[1]);
    bf[6] = (short)f2bf(hi[2]); bf[7] = (short)f2bf(hi[3]);
    const unsigned short* uk = up + kt * 32;
    #pragma unroll
    for (int w = 0; w < 5; ++w) {
      s16x8 av = *(const s16x8*)(uk + w * 16384);   // row w*16 + qrow
      acc[w] = __builtin_amdgcn_mfma_f32_16x16x32_bf16(av, bf, acc[w], 0, 0, 0);
    }
  }

  // s_w = sum_{rows 0..9} c^2 - c_10^2 (rows 11..15 zero-padded)
  float sgn2 = ((lane >> 4) == 2) ? -1.f : 1.f;   // reg 2 of group 2 = row 10
  float sv[5];
  #pragma unroll
  for (int w = 0; w < 5; ++w) {
    float tcc = acc[w][0] * acc[w][0] + acc[w][1] * acc[w][1] +
                sgn2 * acc[w][2] * acc[w][2] + acc[w][3] * acc[w][3];
    tcc += __shfl_xor(tcc, 16);
    tcc += __shfl_xor(tcc, 32);
    sv[w] = tcc;
  }
  float mx = fmaxf(fmaxf(fmaxf(sv[0], sv[1]), fmaxf(sv[2], sv[3])), sv[4]);
  float sum = 0.f;
  #pragma unroll
  for (int w = 0; w < 5; ++w) sum += expf(sv[w] - mx);
  float lse = mx + logf(sum);
  if (lane < 16) {
    float* o = out + (size_t)(q0 + lane) * 5;
    #pragma unroll
    for (int w = 0; w < 5; ++w) o[w] = sv[w] - lse;
  }
}

extern "C" void kernel_launch(void* const* d_in, const int* in_sizes, int n_in,
                              void* d_out, int out_size, void* d_ws, size_t ws_size,
                              hipStream_t stream) {
  const float* support = (const float*)d_in[0];
  const int*   labels  = (const int*)d_in[1];
  const float* query   = (const float*)d_in[2];
  float* out = (float*)d_out;
  char* ws = (char*)d_ws;

  double*         G   = (double*)(ws + WS_G_OFF);
  float*          W   = (float*)(ws + WS_W_OFF);
  int*            idx = (int*)(ws + WS_IDX_OFF);
  unsigned short* U   = (unsigned short*)(ws + WS_U_OFF);

  int nq = in_sizes[2] / 1024;          // 16384
  int nwaves = nq / 16;                 // 1024
  int nblocks = (nwaves + 3) / 4;       // 256

  hipLaunchKernelGGL(dsn_gram,  dim3(69), dim3(256), 0, stream, support, labels, G);
  hipLaunchKernelGGL(dsn_eig,   dim3(1),  dim3(320), 0, stream, labels, G, W, idx);
  hipLaunchKernelGGL(dsn_basis, dim3(80), dim3(256), 0, stream, support, W, idx, U);
  hipLaunchKernelGGL(dsn_main,  dim3(nblocks), dim3(256), 0, stream, query, U, out);
}